// Round 3
// baseline (1893.815 us; speedup 1.0000x reference)
//
#include <hip/hip_runtime.h>

#define N_NODES 100000
#define N_EDGES 1000000
#define N_GRAPHS 128
#define IN_DIM 32
#define HID 64
#define LAT 32
#define N_LAYERS 3

#define MPAD 68  // padded LDS row stride (floats), 16B-aligned rows
#define NB_SUM ((N_NODES + 255) / 256)  // 391 scan blocks

// ---------------- input projection: h = x @ w_in + b_in ----------------
__global__ __launch_bounds__(256) void proj_kernel(
    const float* __restrict__ x, const float* __restrict__ w_in,
    const float* __restrict__ b_in, float* __restrict__ h) {
    __shared__ float ws[IN_DIM * HID];   // 8 KB
    __shared__ float xs[4 * IN_DIM];
    int tid = threadIdx.x;
    for (int i = tid; i < IN_DIM * HID / 4; i += 256)
        ((float4*)ws)[i] = ((const float4*)w_in)[i];
    if (tid < 32) {
        int r = tid >> 3, c4 = tid & 7;
        int nn = blockIdx.x * 4 + r;
        float4 v = make_float4(0.f, 0.f, 0.f, 0.f);
        if (nn < N_NODES) v = ((const float4*)(x + (size_t)nn * IN_DIM))[c4];
        ((float4*)xs)[tid] = v;
    }
    __syncthreads();
    int w = tid >> 6, j = tid & 63;
    int n = blockIdx.x * 4 + w;
    if (n >= N_NODES) return;
    float acc = b_in[j];
#pragma unroll
    for (int k = 0; k < IN_DIM; k += 4) {
        float4 xv = *(const float4*)&xs[w * IN_DIM + k];
        acc += xv.x * ws[(k + 0) * HID + j];
        acc += xv.y * ws[(k + 1) * HID + j];
        acc += xv.z * ws[(k + 2) * HID + j];
        acc += xv.w * ws[(k + 3) * HID + j];
    }
    h[(size_t)n * HID + j] = acc;
}

// ---------------- CSR build ----------------
__global__ __launch_bounds__(256) void hist_kernel(const int* __restrict__ ei,
                                                   int* __restrict__ counts) {
    int e = blockIdx.x * 256 + threadIdx.x;
    if (e < N_EDGES) atomicAdd(&counts[ei[N_EDGES + e]], 1);
}

__global__ __launch_bounds__(256) void block_sum_kernel(
    const int* __restrict__ counts, int* __restrict__ bsums) {
    __shared__ int sd[4];
    int i = blockIdx.x * 256 + threadIdx.x;
    int v = (i < N_NODES) ? counts[i] : 0;
#pragma unroll
    for (int off = 32; off >= 1; off >>= 1) v += __shfl_down(v, off);
    int lane = threadIdx.x & 63, w = threadIdx.x >> 6;
    if (lane == 0) sd[w] = v;
    __syncthreads();
    if (threadIdx.x == 0) bsums[blockIdx.x] = sd[0] + sd[1] + sd[2] + sd[3];
}

__global__ __launch_bounds__(256) void scan_bsums_kernel(
    const int* __restrict__ bsums, int* __restrict__ bofs, int nb) {
    __shared__ int tmp[256];
    __shared__ int carry;
    int tid = threadIdx.x;
    if (tid == 0) carry = 0;
    __syncthreads();
    for (int base = 0; base < nb; base += 256) {
        int v = (base + tid < nb) ? bsums[base + tid] : 0;
        tmp[tid] = v;
        __syncthreads();
        for (int off = 1; off < 256; off <<= 1) {
            int t = (tid >= off) ? tmp[tid - off] : 0;
            __syncthreads();
            tmp[tid] += t;
            __syncthreads();
        }
        if (base + tid < nb) bofs[base + tid] = carry + tmp[tid] - v;
        __syncthreads();
        if (tid == 255) carry += tmp[255];
        __syncthreads();
    }
}

__global__ __launch_bounds__(256) void offsets_kernel(
    const int* __restrict__ counts, const int* __restrict__ bofs,
    int* __restrict__ offsets, int* __restrict__ cursor) {
    __shared__ int tmp[256];
    int tid = threadIdx.x;
    int i = blockIdx.x * 256 + tid;
    int v = (i < N_NODES) ? counts[i] : 0;
    tmp[tid] = v;
    __syncthreads();
    for (int off = 1; off < 256; off <<= 1) {
        int t = (tid >= off) ? tmp[tid - off] : 0;
        __syncthreads();
        tmp[tid] += t;
        __syncthreads();
    }
    int excl = tmp[tid] - v + bofs[blockIdx.x];
    if (i < N_NODES) {
        offsets[i] = excl;
        cursor[i] = excl;
        if (i == N_NODES - 1) offsets[N_NODES] = excl + v;
    }
}

__global__ __launch_bounds__(256) void fill_kernel(const int* __restrict__ ei,
                                                   int* __restrict__ cursor,
                                                   int* __restrict__ srcs) {
    int e = blockIdx.x * 256 + threadIdx.x;
    if (e < N_EDGES) {
        int d = ei[N_EDGES + e];
        int p = atomicAdd(&cursor[d], 1);
        srcs[p] = ei[e];
    }
}

// ---------------- fused layer: gather + GIN MLP ----------------
// block = 64 nodes. Phase 1: each wave gathers agg for 16 nodes (lane=feature),
// writes m = h_in + agg into LDS. Phase 2: two 64x64 GEMMs through LDS with
// 4x4 register micro-tiles. Epilogue: h_out = relu(...) + h_in (skip).
// h double-buffered across layers so gather reads are race-free.
__global__ __launch_bounds__(256, 3) void layer_kernel(
    const float* __restrict__ h_in, float* __restrict__ h_out,
    const int* __restrict__ offsets, const int* __restrict__ srcs,
    const float* __restrict__ w1, const float* __restrict__ b1,
    const float* __restrict__ w2, const float* __restrict__ b2) {
    __shared__ float w1s[HID * HID];   // 16 KB
    __shared__ float w2s[HID * HID];   // 16 KB
    __shared__ float ms[64 * MPAD];    // 17 KB, reused for t
    int tid = threadIdx.x;
    int row0 = blockIdx.x * 64;
    for (int i = tid; i < HID * HID / 4; i += 256) {
        ((float4*)w1s)[i] = ((const float4*)w1)[i];
        ((float4*)w2s)[i] = ((const float4*)w2)[i];
    }

    // ---- gather phase: wave w owns rows [w*16, w*16+16) ----
    int w = tid >> 6, j = tid & 63;
    for (int r = w * 16; r < w * 16 + 16; r++) {
        int n = row0 + r;
        float acc0 = 0.f, acc1 = 0.f;
        if (n < N_NODES) {
            int beg = offsets[n], end = offsets[n + 1];
            for (int c = beg; c < end; c += 64) {
                int myS = (c + j < end) ? srcs[c + j] : 0;
                int m = min(64, end - c);
                int i = 0;
                for (; i + 1 < m; i += 2) {
                    int s0 = __shfl(myS, i);
                    int s1 = __shfl(myS, i + 1);
                    acc0 += h_in[(size_t)s0 * HID + j];
                    acc1 += h_in[(size_t)s1 * HID + j];
                }
                if (i < m) acc0 += h_in[(size_t)__shfl(myS, i) * HID + j];
            }
            acc0 += acc1 + h_in[(size_t)n * HID + j];  // m = agg + h (eps=0)
        }
        ms[r * MPAD + j] = acc0;
    }
    __syncthreads();

    // ---- GEMM phase ----
    int ty = tid >> 4, tx = tid & 15;
    int r0 = ty * 4, c0 = tx * 4;

    float4 a0, a1, a2, a3;
#define GEMM_LDS(WS)                                                          \
    do {                                                                      \
        a0 = make_float4(0.f, 0.f, 0.f, 0.f); a1 = a0; a2 = a0; a3 = a0;      \
        _Pragma("unroll")                                                     \
        for (int k0 = 0; k0 < HID; k0 += 4) {                                 \
            float4 m0 = *(const float4*)&ms[(r0 + 0) * MPAD + k0];            \
            float4 m1 = *(const float4*)&ms[(r0 + 1) * MPAD + k0];            \
            float4 m2 = *(const float4*)&ms[(r0 + 2) * MPAD + k0];            \
            float4 m3 = *(const float4*)&ms[(r0 + 3) * MPAD + k0];            \
            float4 w0 = *(const float4*)&WS[(k0 + 0) * HID + c0];             \
            float4 w1v = *(const float4*)&WS[(k0 + 1) * HID + c0];            \
            float4 w2v = *(const float4*)&WS[(k0 + 2) * HID + c0];            \
            float4 w3v = *(const float4*)&WS[(k0 + 3) * HID + c0];            \
            a0.x += m0.x * w0.x + m0.y * w1v.x + m0.z * w2v.x + m0.w * w3v.x; \
            a0.y += m0.x * w0.y + m0.y * w1v.y + m0.z * w2v.y + m0.w * w3v.y; \
            a0.z += m0.x * w0.z + m0.y * w1v.z + m0.z * w2v.z + m0.w * w3v.z; \
            a0.w += m0.x * w0.w + m0.y * w1v.w + m0.z * w2v.w + m0.w * w3v.w; \
            a1.x += m1.x * w0.x + m1.y * w1v.x + m1.z * w2v.x + m1.w * w3v.x; \
            a1.y += m1.x * w0.y + m1.y * w1v.y + m1.z * w2v.y + m1.w * w3v.y; \
            a1.z += m1.x * w0.z + m1.y * w1v.z + m1.z * w2v.z + m1.w * w3v.z; \
            a1.w += m1.x * w0.w + m1.y * w1v.w + m1.z * w2v.w + m1.w * w3v.w; \
            a2.x += m2.x * w0.x + m2.y * w1v.x + m2.z * w2v.x + m2.w * w3v.x; \
            a2.y += m2.x * w0.y + m2.y * w1v.y + m2.z * w2v.y + m2.w * w3v.y; \
            a2.z += m2.x * w0.z + m2.y * w1v.z + m2.z * w2v.z + m2.w * w3v.z; \
            a2.w += m2.x * w0.w + m2.y * w1v.w + m2.z * w2v.w + m2.w * w3v.w; \
            a3.x += m3.x * w0.x + m3.y * w1v.x + m3.z * w2v.x + m3.w * w3v.x; \
            a3.y += m3.x * w0.y + m3.y * w1v.y + m3.z * w2v.y + m3.w * w3v.y; \
            a3.z += m3.x * w0.z + m3.y * w1v.z + m3.z * w2v.z + m3.w * w3v.z; \
            a3.w += m3.x * w0.w + m3.y * w1v.w + m3.z * w2v.w + m3.w * w3v.w; \
        }                                                                     \
    } while (0)

    GEMM_LDS(w1s);  // GEMM1

    float4 bv1 = *(const float4*)&b1[c0];
    float4 t0, t1, t2, t3;
    t0 = make_float4(fmaxf(a0.x + bv1.x, 0.f), fmaxf(a0.y + bv1.y, 0.f),
                     fmaxf(a0.z + bv1.z, 0.f), fmaxf(a0.w + bv1.w, 0.f));
    t1 = make_float4(fmaxf(a1.x + bv1.x, 0.f), fmaxf(a1.y + bv1.y, 0.f),
                     fmaxf(a1.z + bv1.z, 0.f), fmaxf(a1.w + bv1.w, 0.f));
    t2 = make_float4(fmaxf(a2.x + bv1.x, 0.f), fmaxf(a2.y + bv1.y, 0.f),
                     fmaxf(a2.z + bv1.z, 0.f), fmaxf(a2.w + bv1.w, 0.f));
    t3 = make_float4(fmaxf(a3.x + bv1.x, 0.f), fmaxf(a3.y + bv1.y, 0.f),
                     fmaxf(a3.z + bv1.z, 0.f), fmaxf(a3.w + bv1.w, 0.f));

    __syncthreads();  // all GEMM1 reads of ms complete
    *(float4*)&ms[(r0 + 0) * MPAD + c0] = t0;
    *(float4*)&ms[(r0 + 1) * MPAD + c0] = t1;
    *(float4*)&ms[(r0 + 2) * MPAD + c0] = t2;
    *(float4*)&ms[(r0 + 3) * MPAD + c0] = t3;
    __syncthreads();

    GEMM_LDS(w2s);  // GEMM2

    float4 bv2 = *(const float4*)&b2[c0];
#pragma unroll
    for (int i = 0; i < 4; i++) {
        int n = row0 + r0 + i;
        if (n < N_NODES) {
            float4 av = (i == 0) ? a0 : (i == 1) ? a1 : (i == 2) ? a2 : a3;
            float4 hold = *(const float4*)(h_in + (size_t)n * HID + c0);
            float4 o;
            o.x = fmaxf(av.x + bv2.x, 0.f) + hold.x;
            o.y = fmaxf(av.y + bv2.y, 0.f) + hold.y;
            o.z = fmaxf(av.z + bv2.z, 0.f) + hold.z;
            o.w = fmaxf(av.w + bv2.w, 0.f) + hold.w;
            *(float4*)(h_out + (size_t)n * HID + c0) = o;
        }
    }
#undef GEMM_LDS
}

// ---------------- global add pool ----------------
__global__ __launch_bounds__(256) void pool_kernel(
    const float* __restrict__ h, const int* __restrict__ batch,
    float* __restrict__ pooled) {
    int tid = threadIdx.x;
    int w = tid >> 6, j = tid & 63;
    int n0 = blockIdx.x * 256 + w * 64;
    if (n0 >= N_NODES) return;
    int nend = min(n0 + 64, N_NODES);
    float acc = 0.f;
    int cur = batch[n0];
    for (int n = n0; n < nend; n++) {
        int b = batch[n];
        if (b != cur) {
            atomicAdd(&pooled[cur * HID + j], acc);
            acc = 0.f;
            cur = b;
        }
        acc += h[(size_t)n * HID + j];
    }
    atomicAdd(&pooled[cur * HID + j], acc);
}

// ---------------- final FC ----------------
__global__ __launch_bounds__(256) void final_kernel(
    const float* __restrict__ pooled, const float* __restrict__ w_fc,
    const float* __restrict__ b_fc, float* __restrict__ out) {
    int gid = blockIdx.x * 256 + threadIdx.x;
    if (gid >= N_GRAPHS * LAT) return;
    int g = gid >> 5, j = gid & 31;
    float acc = b_fc[j];
#pragma unroll
    for (int k = 0; k < HID; k++)
        acc += pooled[g * HID + k] * w_fc[k * LAT + j];
    out[gid] = acc;
}

extern "C" void kernel_launch(void* const* d_in, const int* in_sizes, int n_in,
                              void* d_out, int out_size, void* d_ws,
                              size_t ws_size, hipStream_t stream) {
    const float* x     = (const float*)d_in[0];
    const int*   ei    = (const int*)d_in[1];
    const int*   batch = (const int*)d_in[2];
    const float* w_in  = (const float*)d_in[3];
    const float* b_in  = (const float*)d_in[4];
    const float* w1    = (const float*)d_in[5];
    const float* b1    = (const float*)d_in[6];
    const float* w2    = (const float*)d_in[7];
    const float* b2    = (const float*)d_in[8];
    const float* w_fc  = (const float*)d_in[9];
    const float* b_fc  = (const float*)d_in[10];
    float* out = (float*)d_out;

    // persistent: h0 | h1 | pooled | offsets | srcs  (~56 MB)
    float* h0      = (float*)d_ws;
    float* h1      = h0 + (size_t)N_NODES * HID;
    float* pooled  = h1 + (size_t)N_NODES * HID;
    int*   offsets = (int*)(pooled + N_GRAPHS * HID);   // N_NODES+1
    int*   srcs    = offsets + (N_NODES + 2);           // N_EDGES
    // CSR build scratch overlaid into h1 (dead before layer 0 writes h1)
    int* counts = (int*)h1;             // N_NODES
    int* cursor = counts + N_NODES;     // N_NODES
    int* bsums  = cursor + N_NODES;     // NB_SUM
    int* bofs   = bsums + (NB_SUM + 1); // NB_SUM

    proj_kernel<<<(N_NODES + 3) / 4, 256, 0, stream>>>(x, w_in, b_in, h0);

    // CSR build (once; edges constant across layers)
    hipMemsetAsync(counts, 0, N_NODES * sizeof(int), stream);
    hist_kernel<<<(N_EDGES + 255) / 256, 256, 0, stream>>>(ei, counts);
    block_sum_kernel<<<NB_SUM, 256, 0, stream>>>(counts, bsums);
    scan_bsums_kernel<<<1, 256, 0, stream>>>(bsums, bofs, NB_SUM);
    offsets_kernel<<<NB_SUM, 256, 0, stream>>>(counts, bofs, offsets, cursor);
    fill_kernel<<<(N_EDGES + 255) / 256, 256, 0, stream>>>(ei, cursor, srcs);

    // fused layers, h double-buffered: h0->h1->h0->h1
    const float* hin = h0;
    float* hout = h1;
    for (int i = 0; i < N_LAYERS; i++) {
        layer_kernel<<<(N_NODES + 63) / 64, 256, 0, stream>>>(
            hin, hout, offsets, srcs,
            w1 + (size_t)i * HID * HID, b1 + (size_t)i * HID,
            w2 + (size_t)i * HID * HID, b2 + (size_t)i * HID);
        const float* tmp = hout;
        hout = (float*)hin;
        hin = tmp;
    }

    hipMemsetAsync(pooled, 0, N_GRAPHS * HID * sizeof(float), stream);
    pool_kernel<<<(N_NODES + 255) / 256, 256, 0, stream>>>(hin, batch, pooled);
    final_kernel<<<(N_GRAPHS * LAT + 255) / 256, 256, 0, stream>>>(
        pooled, w_fc, b_fc, out);
}

// Round 4
// 489.822 us; speedup vs baseline: 3.8663x; 3.8663x over previous
//
#include <hip/hip_runtime.h>

#define N_NODES 100000
#define N_EDGES 1000000
#define N_GRAPHS 128
#define IN_DIM 32
#define HID 64
#define LAT 32
#define N_LAYERS 3

#define MPAD 68  // padded LDS row stride (floats), 16B-aligned rows
#define NB_SUM ((N_NODES + 255) / 256)  // 391 scan blocks

// ---------------- input projection: h = x @ w_in + b_in ----------------
__global__ __launch_bounds__(256) void proj_kernel(
    const float* __restrict__ x, const float* __restrict__ w_in,
    const float* __restrict__ b_in, float* __restrict__ h) {
    __shared__ float ws[IN_DIM * HID];   // 8 KB
    __shared__ float xs[4 * IN_DIM];
    int tid = threadIdx.x;
    for (int i = tid; i < IN_DIM * HID / 4; i += 256)
        ((float4*)ws)[i] = ((const float4*)w_in)[i];
    if (tid < 32) {
        int r = tid >> 3, c4 = tid & 7;
        int nn = blockIdx.x * 4 + r;
        float4 v = make_float4(0.f, 0.f, 0.f, 0.f);
        if (nn < N_NODES) v = ((const float4*)(x + (size_t)nn * IN_DIM))[c4];
        ((float4*)xs)[tid] = v;
    }
    __syncthreads();
    int w = tid >> 6, j = tid & 63;
    int n = blockIdx.x * 4 + w;
    if (n >= N_NODES) return;
    float acc = b_in[j];
#pragma unroll
    for (int k = 0; k < IN_DIM; k += 4) {
        float4 xv = *(const float4*)&xs[w * IN_DIM + k];
        acc += xv.x * ws[(k + 0) * HID + j];
        acc += xv.y * ws[(k + 1) * HID + j];
        acc += xv.z * ws[(k + 2) * HID + j];
        acc += xv.w * ws[(k + 3) * HID + j];
    }
    h[(size_t)n * HID + j] = acc;
}

// ---------------- CSR build ----------------
__global__ __launch_bounds__(256) void hist_kernel(const int* __restrict__ ei,
                                                   int* __restrict__ counts) {
    int e = blockIdx.x * 256 + threadIdx.x;
    if (e < N_EDGES) atomicAdd(&counts[ei[N_EDGES + e]], 1);
}

__global__ __launch_bounds__(256) void block_sum_kernel(
    const int* __restrict__ counts, int* __restrict__ bsums) {
    __shared__ int sd[4];
    int i = blockIdx.x * 256 + threadIdx.x;
    int v = (i < N_NODES) ? counts[i] : 0;
#pragma unroll
    for (int off = 32; off >= 1; off >>= 1) v += __shfl_down(v, off);
    int lane = threadIdx.x & 63, w = threadIdx.x >> 6;
    if (lane == 0) sd[w] = v;
    __syncthreads();
    if (threadIdx.x == 0) bsums[blockIdx.x] = sd[0] + sd[1] + sd[2] + sd[3];
}

__global__ __launch_bounds__(256) void scan_bsums_kernel(
    const int* __restrict__ bsums, int* __restrict__ bofs, int nb) {
    __shared__ int tmp[256];
    __shared__ int carry;
    int tid = threadIdx.x;
    if (tid == 0) carry = 0;
    __syncthreads();
    for (int base = 0; base < nb; base += 256) {
        int v = (base + tid < nb) ? bsums[base + tid] : 0;
        tmp[tid] = v;
        __syncthreads();
        for (int off = 1; off < 256; off <<= 1) {
            int t = (tid >= off) ? tmp[tid - off] : 0;
            __syncthreads();
            tmp[tid] += t;
            __syncthreads();
        }
        if (base + tid < nb) bofs[base + tid] = carry + tmp[tid] - v;
        __syncthreads();
        if (tid == 255) carry += tmp[255];
        __syncthreads();
    }
}

__global__ __launch_bounds__(256) void offsets_kernel(
    const int* __restrict__ counts, const int* __restrict__ bofs,
    int* __restrict__ offsets, int* __restrict__ cursor) {
    __shared__ int tmp[256];
    int tid = threadIdx.x;
    int i = blockIdx.x * 256 + tid;
    int v = (i < N_NODES) ? counts[i] : 0;
    tmp[tid] = v;
    __syncthreads();
    for (int off = 1; off < 256; off <<= 1) {
        int t = (tid >= off) ? tmp[tid - off] : 0;
        __syncthreads();
        tmp[tid] += t;
        __syncthreads();
    }
    int excl = tmp[tid] - v + bofs[blockIdx.x];
    if (i < N_NODES) {
        offsets[i] = excl;
        cursor[i] = excl;
        if (i == N_NODES - 1) offsets[N_NODES] = excl + v;
    }
}

__global__ __launch_bounds__(256) void fill_kernel(const int* __restrict__ ei,
                                                   int* __restrict__ cursor,
                                                   int* __restrict__ srcs) {
    int e = blockIdx.x * 256 + threadIdx.x;
    if (e < N_EDGES) {
        int d = ei[N_EDGES + e];
        int p = atomicAdd(&cursor[d], 1);
        srcs[p] = ei[e];
    }
}

// ---------------- gather: agg[n] = sum_{e in in(n)} h[src[e]] ----------------
// one wave per node; lane j owns feature j; 4 independent load chains for ILP
__global__ __launch_bounds__(256) void gather_kernel(
    const int* __restrict__ offsets, const int* __restrict__ srcs,
    const float* __restrict__ h, float* __restrict__ agg) {
    int w = threadIdx.x >> 6, j = threadIdx.x & 63;
    int n = blockIdx.x * 4 + w;
    if (n >= N_NODES) return;
    int beg = offsets[n], end = offsets[n + 1];
    float acc0 = 0.f, acc1 = 0.f, acc2 = 0.f, acc3 = 0.f;
    for (int c = beg; c < end; c += 64) {
        int myS = (c + j < end) ? srcs[c + j] : 0;
        int m = min(64, end - c);
        int i = 0;
        for (; i + 3 < m; i += 4) {
            int s0 = __shfl(myS, i);
            int s1 = __shfl(myS, i + 1);
            int s2 = __shfl(myS, i + 2);
            int s3 = __shfl(myS, i + 3);
            acc0 += h[(size_t)s0 * HID + j];
            acc1 += h[(size_t)s1 * HID + j];
            acc2 += h[(size_t)s2 * HID + j];
            acc3 += h[(size_t)s3 * HID + j];
        }
        for (; i < m; i++) acc0 += h[(size_t)__shfl(myS, i) * HID + j];
    }
    agg[(size_t)n * HID + j] = acc0 + acc1 + acc2 + acc3;
}

// ---------------- fused GIN MLP ----------------
// 512 threads, 64-node tile, 2x4 register micro-tile (8 accs) to keep VGPR
// low WITHOUT a launch_bounds min-waves clause (R3 lesson: that forces spills).
__global__ __launch_bounds__(512) void mlp_kernel(
    float* __restrict__ h, const float* __restrict__ agg,
    const float* __restrict__ w1, const float* __restrict__ b1,
    const float* __restrict__ w2, const float* __restrict__ b2) {
    __shared__ float w1s[HID * HID];   // 16 KB
    __shared__ float w2s[HID * HID];   // 16 KB
    __shared__ float ms[64 * MPAD];    // 17 KB, reused for t
    int tid = threadIdx.x;
    int row0 = blockIdx.x * 64;
    for (int i = tid; i < HID * HID / 4; i += 512) {
        ((float4*)w1s)[i] = ((const float4*)w1)[i];
        ((float4*)w2s)[i] = ((const float4*)w2)[i];
    }
#pragma unroll
    for (int i = 0; i < 2; i++) {
        int f = tid + i * 512;
        int r = f >> 4, c4 = f & 15;
        int n = row0 + r;
        float4 mv = make_float4(0.f, 0.f, 0.f, 0.f);
        if (n < N_NODES) {
            float4 h4 = ((const float4*)(h + (size_t)n * HID))[c4];
            float4 a4 = ((const float4*)(agg + (size_t)n * HID))[c4];
            mv = make_float4(h4.x + a4.x, h4.y + a4.y, h4.z + a4.z, h4.w + a4.w);
        }
        *(float4*)&ms[r * MPAD + c4 * 4] = mv;
    }
    __syncthreads();

    int ty = tid >> 4, tx = tid & 15;   // ty 0..31, tx 0..15
    int r0 = ty * 2, c0 = tx * 4;

    float4 a0, a1;
#define GEMM_LDS(WS)                                                          \
    do {                                                                      \
        a0 = make_float4(0.f, 0.f, 0.f, 0.f); a1 = a0;                        \
        _Pragma("unroll 4")                                                   \
        for (int k0 = 0; k0 < HID; k0 += 4) {                                 \
            float4 m0 = *(const float4*)&ms[(r0 + 0) * MPAD + k0];            \
            float4 m1 = *(const float4*)&ms[(r0 + 1) * MPAD + k0];            \
            float4 w0 = *(const float4*)&WS[(k0 + 0) * HID + c0];             \
            float4 w1v = *(const float4*)&WS[(k0 + 1) * HID + c0];            \
            float4 w2v = *(const float4*)&WS[(k0 + 2) * HID + c0];            \
            float4 w3v = *(const float4*)&WS[(k0 + 3) * HID + c0];            \
            a0.x += m0.x * w0.x + m0.y * w1v.x + m0.z * w2v.x + m0.w * w3v.x; \
            a0.y += m0.x * w0.y + m0.y * w1v.y + m0.z * w2v.y + m0.w * w3v.y; \
            a0.z += m0.x * w0.z + m0.y * w1v.z + m0.z * w2v.z + m0.w * w3v.z; \
            a0.w += m0.x * w0.w + m0.y * w1v.w + m0.z * w2v.w + m0.w * w3v.w; \
            a1.x += m1.x * w0.x + m1.y * w1v.x + m1.z * w2v.x + m1.w * w3v.x; \
            a1.y += m1.x * w0.y + m1.y * w1v.y + m1.z * w2v.y + m1.w * w3v.y; \
            a1.z += m1.x * w0.z + m1.y * w1v.z + m1.z * w2v.z + m1.w * w3v.z; \
            a1.w += m1.x * w0.w + m1.y * w1v.w + m1.z * w2v.w + m1.w * w3v.w; \
        }                                                                     \
    } while (0)

    GEMM_LDS(w1s);  // GEMM1

    float4 bv1 = *(const float4*)&b1[c0];
    float4 t0 = make_float4(fmaxf(a0.x + bv1.x, 0.f), fmaxf(a0.y + bv1.y, 0.f),
                            fmaxf(a0.z + bv1.z, 0.f), fmaxf(a0.w + bv1.w, 0.f));
    float4 t1 = make_float4(fmaxf(a1.x + bv1.x, 0.f), fmaxf(a1.y + bv1.y, 0.f),
                            fmaxf(a1.z + bv1.z, 0.f), fmaxf(a1.w + bv1.w, 0.f));

    __syncthreads();  // all GEMM1 reads of ms complete
    *(float4*)&ms[(r0 + 0) * MPAD + c0] = t0;
    *(float4*)&ms[(r0 + 1) * MPAD + c0] = t1;
    __syncthreads();

    GEMM_LDS(w2s);  // GEMM2

    float4 bv2 = *(const float4*)&b2[c0];
#pragma unroll
    for (int i = 0; i < 2; i++) {
        int n = row0 + r0 + i;
        if (n < N_NODES) {
            float4 av = (i == 0) ? a0 : a1;
            float4 hold = *(const float4*)(h + (size_t)n * HID + c0);
            float4 o;
            o.x = fmaxf(av.x + bv2.x, 0.f) + hold.x;
            o.y = fmaxf(av.y + bv2.y, 0.f) + hold.y;
            o.z = fmaxf(av.z + bv2.z, 0.f) + hold.z;
            o.w = fmaxf(av.w + bv2.w, 0.f) + hold.w;
            *(float4*)(h + (size_t)n * HID + c0) = o;
        }
    }
#undef GEMM_LDS
}

// ---------------- global add pool ----------------
__global__ __launch_bounds__(256) void pool_kernel(
    const float* __restrict__ h, const int* __restrict__ batch,
    float* __restrict__ pooled) {
    int tid = threadIdx.x;
    int w = tid >> 6, j = tid & 63;
    int n0 = blockIdx.x * 256 + w * 64;
    if (n0 >= N_NODES) return;
    int nend = min(n0 + 64, N_NODES);
    float acc = 0.f;
    int cur = batch[n0];
    for (int n = n0; n < nend; n++) {
        int b = batch[n];
        if (b != cur) {
            atomicAdd(&pooled[cur * HID + j], acc);
            acc = 0.f;
            cur = b;
        }
        acc += h[(size_t)n * HID + j];
    }
    atomicAdd(&pooled[cur * HID + j], acc);
}

// ---------------- final FC ----------------
__global__ __launch_bounds__(256) void final_kernel(
    const float* __restrict__ pooled, const float* __restrict__ w_fc,
    const float* __restrict__ b_fc, float* __restrict__ out) {
    int gid = blockIdx.x * 256 + threadIdx.x;
    if (gid >= N_GRAPHS * LAT) return;
    int g = gid >> 5, j = gid & 31;
    float acc = b_fc[j];
#pragma unroll
    for (int k = 0; k < HID; k++)
        acc += pooled[g * HID + k] * w_fc[k * LAT + j];
    out[gid] = acc;
}

extern "C" void kernel_launch(void* const* d_in, const int* in_sizes, int n_in,
                              void* d_out, int out_size, void* d_ws,
                              size_t ws_size, hipStream_t stream) {
    const float* x     = (const float*)d_in[0];
    const int*   ei    = (const int*)d_in[1];
    const int*   batch = (const int*)d_in[2];
    const float* w_in  = (const float*)d_in[3];
    const float* b_in  = (const float*)d_in[4];
    const float* w1    = (const float*)d_in[5];
    const float* b1    = (const float*)d_in[6];
    const float* w2    = (const float*)d_in[7];
    const float* b2    = (const float*)d_in[8];
    const float* w_fc  = (const float*)d_in[9];
    const float* b_fc  = (const float*)d_in[10];
    float* out = (float*)d_out;

    // persistent: h | agg | pooled | offsets | srcs   (~56 MB)
    float* h       = (float*)d_ws;
    float* agg     = h + (size_t)N_NODES * HID;
    float* pooled  = agg + (size_t)N_NODES * HID;
    int*   offsets = (int*)(pooled + N_GRAPHS * HID);   // N_NODES+1
    int*   srcs    = offsets + (N_NODES + 2);           // N_EDGES
    // build-time arrays overlaid into agg's region (dead before first gather)
    int* counts = (int*)agg;            // N_NODES
    int* cursor = counts + N_NODES;     // N_NODES
    int* bsums  = cursor + N_NODES;     // NB_SUM
    int* bofs   = bsums + (NB_SUM + 1); // NB_SUM

    proj_kernel<<<(N_NODES + 3) / 4, 256, 0, stream>>>(x, w_in, b_in, h);

    // CSR build (once; edges constant across layers)
    hipMemsetAsync(counts, 0, N_NODES * sizeof(int), stream);
    hist_kernel<<<(N_EDGES + 255) / 256, 256, 0, stream>>>(ei, counts);
    block_sum_kernel<<<NB_SUM, 256, 0, stream>>>(counts, bsums);
    scan_bsums_kernel<<<1, 256, 0, stream>>>(bsums, bofs, NB_SUM);
    offsets_kernel<<<NB_SUM, 256, 0, stream>>>(counts, bofs, offsets, cursor);
    fill_kernel<<<(N_EDGES + 255) / 256, 256, 0, stream>>>(ei, cursor, srcs);

    for (int i = 0; i < N_LAYERS; i++) {
        gather_kernel<<<(N_NODES + 3) / 4, 256, 0, stream>>>(offsets, srcs, h, agg);
        mlp_kernel<<<(N_NODES + 63) / 64, 512, 0, stream>>>(
            h, agg, w1 + (size_t)i * HID * HID, b1 + (size_t)i * HID,
            w2 + (size_t)i * HID * HID, b2 + (size_t)i * HID);
    }

    hipMemsetAsync(pooled, 0, N_GRAPHS * HID * sizeof(float), stream);
    pool_kernel<<<(N_NODES + 255) / 256, 256, 0, stream>>>(h, batch, pooled);
    final_kernel<<<(N_GRAPHS * LAT + 255) / 256, 256, 0, stream>>>(
        pooled, w_fc, b_fc, out);
}